// Round 11
// baseline (284.201 us; speedup 1.0000x reference)
//
#include <hip/hip_runtime.h>

// Problem constants (match reference file)
constexpr int B = 32768;
constexpr int D = 1024;
constexpr int S = 64;
constexpr int O = 4;

// ---------------------------------------------------------------------------
// R11 = R10 (best, 187.1us: W^T in LDS, ballot compaction, block-shared
// virtual list, 2x oversubscription, nt x-loads, 12-shuffle reduce) with ONE
// change: the steady loop is a TWO-ROW register pipeline under
// amdgpu_waves_per_eu(4,4).
//
// Rationale: corrected floor model (R4: total 230.8 with main=93.2 -> fixed
// harness portion ~137.6us) says R10's custom part is ~49.5us vs a ~23us
// floor -- 2.2x above roofline, read-concurrency-bound (R8's nt = -10us is
// the fingerprint).  R10's single xb buffer caps each wave at ONE row (4KB)
// intermittently in flight: loads can only issue after the previous row's
// FMA consumed the buffer.  Depth-2 in registers needs ~75 VGPR; the
// default allocator picks 64 and spills (R4).  waves_per_eu(4,4) raises the
// budget to 128 (attribute proven effective in R6) at 16 waves/CU -- VALU
// slack is still >=2x requirement, and each wave now keeps 8 loads (2 rows)
// continuously outstanding, issued ~2 iterations (~500cy) before use.
// R9 failed at depth because it paid LDS occupancy (50KB ring -> 12 waves)
// and rigid per-row vmcnt; this pays neither (LDS unchanged 17.3KB).
// ---------------------------------------------------------------------------

constexpr int CHUNKS      = 64;             // chunks per subject
constexpr int CHUNK       = B / CHUNKS;     // 512 rows per block
constexpr int WSEG        = CHUNK / 4;      // 128 rows scanned per wave
constexpr int MAIN_BLOCKS = S * CHUNKS;     // 4096 blocks

typedef float f4 __attribute__((ext_vector_type(4)));

__global__ __launch_bounds__(256)
__attribute__((amdgpu_waves_per_eu(4, 4)))
void main_kernel(
    const float* __restrict__ x,      // [B, D]
    const int*   __restrict__ sid,    // [B]
    const float* __restrict__ W,      // [S, D, O]
    const float* __restrict__ bias,   // [S, O]
    float*       __restrict__ out)    // [B, O]
{
    __shared__ float          Wt[O * D];        // 16 KB: plane o at Wt[o*1024+d]
    __shared__ unsigned short wlist[4][WSEG];   //  1 KB: per-wave match lists
    __shared__ int            wcnt[4];

    const int t    = threadIdx.x;
    const int lane = t & 63;
    const int wave = t >> 6;
    const int s    = blockIdx.x >> 6;         // 64 consecutive blocks share s
    const int c    = blockIdx.x & 63;
    const int q    = lane >> 4;               // output index this lane stores

    // ---- 1. Stage W[s]^T into LDS (coalesced float4 reads; scalar writes
    //         bank = d%32 = t%32, 2 lanes/bank = free). ----
    {
        const f4* Wp = (const f4*)(W + (size_t)s * (D * O));
        #pragma unroll
        for (int r = 0; r < 4; ++r) {
            const int d = r * 256 + t;
            const f4 w4 = Wp[d];              // W[s][d][0..3]
            Wt[0 * D + d] = w4.x;
            Wt[1 * D + d] = w4.y;
            Wt[2 * D + d] = w4.z;
            Wt[3 * D + d] = w4.w;
        }
    }

    // ---- 2. Scan my 128-row sid segment, ballot-compact into my list. ----
    const int seg = c * CHUNK + wave * WSEG;
    int cnt = 0;
    #pragma unroll
    for (int r = 0; r < 2; ++r) {
        const int i = seg + r * 64 + lane;                 // coalesced 256B
        const bool m = (sid[i] == s);
        const unsigned long long mask = __ballot(m);
        const int rank = __popcll(mask & ((1ull << lane) - 1ull));
        if (m) wlist[wave][cnt + rank] = (unsigned short)i;
        cnt += __popcll(mask);                             // lane-uniform
    }
    if (lane == 0) wcnt[wave] = cnt;

    const float bb = bias[(s << 2) + q];

    __syncthreads();                          // Wt + wlist + wcnt visible

    // ---- 3. Virtual concatenated list; wave w takes entries w, w+4, ... ----
    const int c0 = wcnt[0], c1 = wcnt[1], c2 = wcnt[2], c3 = wcnt[3];
    const int p1 = c0, p2 = c0 + c1, p3 = c0 + c1 + c2;
    const int total = p3 + c3;

#define ROW_OF(G, DST) do {                                                    \
        int _g = (G), _r;                                                      \
        if      (_g < p1) _r = wlist[0][_g];                                   \
        else if (_g < p2) _r = wlist[1][_g - p1];                              \
        else if (_g < p3) _r = wlist[2][_g - p2];                              \
        else              _r = wlist[3][_g - p3];                              \
        (DST) = __builtin_amdgcn_readfirstlane(_r);                            \
    } while (0)

#define LOADX(XB, ROW)                                                         \
    {                                                                          \
        const f4* _xr = (const f4*)(x + ((size_t)(ROW) << 10));                \
        _Pragma("unroll")                                                      \
        for (int _j = 0; _j < 4; ++_j)                                         \
            XB[_j] = __builtin_nontemporal_load(_xr + 64 * _j + lane);         \
    }

    int g = wave;
    if (g >= total) return;                   // wave-uniform exit

    const f4* Wt4 = (const f4*)Wt;            // plane o at f4 index o*256

    // ---- 4. Two-row register pipeline.  Invariant at each PHASE entry:
    //         XC holds row rowC (= entry g), XN holds row rowN (= entry g+4,
    //         in flight).  PHASE: FMA(XC) -> issue entry g+8 into XC ->
    //         reduce -> store -> rotate.  8 loads / 2 rows always in flight.
    float4_dummy_guard: ;
    f4 xbA[4], xbB[4];
    int rowC, rowN;
    ROW_OF(g, rowC);
    LOADX(xbA, rowC)
    rowN = rowC;
    if (g + 4 < total) {
        ROW_OF(g + 4, rowN);
        LOADX(xbB, rowN)
    }

#define PHASE(XC, XN)                                                          \
    {                                                                          \
        float a0 = 0.f, a1 = 0.f, a2 = 0.f, a3 = 0.f;                          \
        _Pragma("unroll")                                                      \
        for (int j = 0; j < 4; ++j) {                                          \
            const f4 xv = XC[j];                                               \
            const f4 w0 = Wt4[0 * 256 + 64 * j + lane];  /* 16B lane stride */ \
            const f4 w1 = Wt4[1 * 256 + 64 * j + lane];  /* conflict-free  */  \
            const f4 w2 = Wt4[2 * 256 + 64 * j + lane];                        \
            const f4 w3 = Wt4[3 * 256 + 64 * j + lane];                        \
            a0 += xv.x * w0.x; a1 += xv.x * w1.x;                              \
            a2 += xv.x * w2.x; a3 += xv.x * w3.x;                              \
            a0 += xv.y * w0.y; a1 += xv.y * w1.y;                              \
            a2 += xv.y * w2.y; a3 += xv.y * w3.y;                              \
            a0 += xv.z * w0.z; a1 += xv.z * w1.z;                              \
            a2 += xv.z * w2.z; a3 += xv.z * w3.z;                              \
            a0 += xv.w * w0.w; a1 += xv.w * w1.w;                              \
            a2 += xv.w * w2.w; a3 += xv.w * w3.w;                              \
        }                                                                      \
        int rowP = rowC;                                                       \
        if (g + 8 < total) {                  /* refill just-consumed buf */   \
            ROW_OF(g + 8, rowP);                                               \
            LOADX(XC, rowP)                                                    \
        }                                                                      \
        _Pragma("unroll")                                                      \
        for (int m = 16; m <= 32; m <<= 1) {                                   \
            a0 += __shfl_xor(a0, m, 64);                                       \
            a1 += __shfl_xor(a1, m, 64);                                       \
            a2 += __shfl_xor(a2, m, 64);                                       \
            a3 += __shfl_xor(a3, m, 64);                                       \
        }                                                                      \
        float v = (q == 0) ? a0 : (q == 1) ? a1 : (q == 2) ? a2 : a3;          \
        _Pragma("unroll")                                                      \
        for (int m = 1; m <= 8; m <<= 1)                                       \
            v += __shfl_xor(v, m, 64);                                         \
        if ((lane & 15) == 0)                 /* lanes 0,16,32,48 -> o=0..3 */ \
            out[((size_t)rowC << 2) + q] = v + bb;                             \
        rowC = rowN; rowN = rowP; g += 4;                                      \
    }

    #pragma unroll 1
    for (;;) {
        PHASE(xbA, xbB)
        if (g >= total) break;
        PHASE(xbB, xbA)
        if (g >= total) break;
    }

#undef PHASE
#undef LOADX
#undef ROW_OF
}

extern "C" void kernel_launch(void* const* d_in, const int* in_sizes, int n_in,
                              void* d_out, int out_size, void* d_ws, size_t ws_size,
                              hipStream_t stream) {
    const float* x    = (const float*)d_in[0];   // [B, D]
    const int*   sid  = (const int*)d_in[1];     // [B]
    const float* W    = (const float*)d_in[2];   // [S, D, O]
    const float* bias = (const float*)d_in[3];   // [S, O]
    float* out = (float*)d_out;                  // [B, O]

    main_kernel<<<MAIN_BLOCKS, 256, 0, stream>>>(x, sid, W, bias, out);
}